// Round 5
// baseline (1262.157 us; speedup 1.0000x reference)
//
#include <hip/hip_runtime.h>

#define B_ROWS 32768
#define D_NETS 16
#define MW     1048576   // 1024*1024
#define PKL    131072    // pack-chunks (8 elem) per 1024x1024 layer

typedef __attribute__((ext_vector_type(8)))  short bf16x8;
typedef __attribute__((ext_vector_type(16))) float f32x16;

__device__ __forceinline__ ushort bf16_rne(float f) {
    unsigned u = __float_as_uint(f);
    unsigned r = u + 0x7FFFu + ((u >> 16) & 1u);
    return (ushort)(r >> 16);
}
__device__ __forceinline__ float bf16_to_f(ushort h) {
    return __uint_as_float(((unsigned)h) << 16);
}
#define MFMA __builtin_amdgcn_mfma_f32_32x32x16_bf16

// ---------------------------------------------------------------------------
// prep: split gW2/gW3/gW4 into bf16 hi/lo, MFMA-fragment-linear packed:
// Wpack[((ks*32+g)*64 + lane)*8 + kk], lane = khalf*32 + (n&31).
// ws: W2h@0, W2l@1M, W3h@2M, W3l@3M, W4h@4M, W4l@5M, W1h@6M, W1l@6M+16384
// ---------------------------------------------------------------------------
__global__ void pack_weights(const float* __restrict__ gW1,
                             const float* __restrict__ gW2,
                             const float* __restrict__ gW3,
                             const float* __restrict__ gW4,
                             ushort* __restrict__ ws) {
    const int p = blockIdx.x * 256 + threadIdx.x;
    if (p < 3 * PKL) {
        const int lz = p / PKL;
        const int pl = p - lz * PKL;
        const float* W = (lz == 0) ? gW2 : ((lz == 1) ? gW3 : gW4);
        const int l  = pl & 63;
        const int g  = (pl >> 6) & 31;
        const int ks = pl >> 11;
        const int n  = g * 32 + (l & 31);
        const int k0 = ks * 16 + (l >> 5) * 8;
        const float* src = &W[n * 1024 + k0];
        ushort* dh = &ws[(size_t)lz * 2 * MW + (size_t)pl * 8];
        ushort* dl = dh + MW;
        #pragma unroll
        for (int kk = 0; kk < 8; ++kk) {
            float w = src[kk];
            ushort h = bf16_rne(w);
            dh[kk] = h;
            dl[kk] = bf16_rne(w - bf16_to_f(h));
        }
    } else {
        const int pl = p - 3 * PKL;
        if (pl >= 2048) return;
        const float* src = &gW1[pl * 8];
        ushort* dh = &ws[6 * MW + pl * 8];
        ushort* dl = dh + 16384;
        #pragma unroll
        for (int kk = 0; kk < 8; ++kk) {
            float w = src[kk];
            ushort h = bf16_rne(w);
            dh[kk] = h;
            dl[kk] = bf16_rne(w - bf16_to_f(h));
        }
    }
}

// ---------------------------------------------------------------------------
// h-network: unchanged.
// ---------------------------------------------------------------------------
__global__ __launch_bounds__(256, 1) void h_net_kernel(
    const float* __restrict__ x,
    const float* __restrict__ hW1, const float* __restrict__ hb1,
    const float* __restrict__ hW2, const float* __restrict__ hb2,
    const float* __restrict__ hW3, const float* __restrict__ hb3,
    const float* __restrict__ hW4, const float* __restrict__ hb4,
    const float* __restrict__ hW5, const float* __restrict__ hb5,
    float* __restrict__ out)
{
    __shared__ float s_w[3 * 4096];
    __shared__ float s_w1[64];
    __shared__ float s_b1[64];
    __shared__ float s_bs[3 * 64];
    __shared__ float s_w5[64];
    __shared__ float s_b5;

    const int d = blockIdx.y;
    const int t = threadIdx.x;

    for (int i = t; i < 4096; i += 256) {
        s_w[i]        = hW2[d * 4096 + i];
        s_w[4096 + i] = hW3[d * 4096 + i];
        s_w[8192 + i] = hW4[d * 4096 + i];
    }
    if (t < 64) {
        s_w1[t]       = hW1[d * 64 + t];
        s_b1[t]       = hb1[d * 64 + t];
        s_bs[t]       = hb2[d * 64 + t];
        s_bs[64 + t]  = hb3[d * 64 + t];
        s_bs[128 + t] = hb4[d * 64 + t];
        s_w5[t]       = hW5[d * 64 + t];
        if (t == 0) s_b5 = hb5[d];
    }
    __syncthreads();

    const int row = blockIdx.x * 256 + t;
    const float sv = x[row * 32 + 16 + d];

    float ha[64];
    #pragma unroll
    for (int j = 0; j < 64; ++j)
        ha[j] = fmaxf(fmaf(sv, s_w1[j], s_b1[j]), 0.0f);

    #pragma unroll 1
    for (int L = 0; L < 3; ++L) {
        const float* W  = &s_w[L * 4096];
        const float* bb = &s_bs[L * 64];
        float hn[64];
        #pragma unroll
        for (int g = 0; g < 64; ++g) {
            float a0 = bb[g], a1 = 0.f, a2 = 0.f, a3 = 0.f;
            #pragma unroll
            for (int h4 = 0; h4 < 16; ++h4) {
                float4 wv = *reinterpret_cast<const float4*>(&W[g * 64 + h4 * 4]);
                a0 = fmaf(ha[h4 * 4 + 0], wv.x, a0);
                a1 = fmaf(ha[h4 * 4 + 1], wv.y, a1);
                a2 = fmaf(ha[h4 * 4 + 2], wv.z, a2);
                a3 = fmaf(ha[h4 * 4 + 3], wv.w, a3);
            }
            hn[g] = fmaxf((a0 + a1) + (a2 + a3), 0.0f);
        }
        #pragma unroll
        for (int j = 0; j < 64; ++j) ha[j] = hn[j];
    }

    float o0 = 0.f, o1 = 0.f, o2 = 0.f, o3 = 0.f;
    #pragma unroll
    for (int h4 = 0; h4 < 16; ++h4) {
        o0 = fmaf(ha[h4 * 4 + 0], s_w5[h4 * 4 + 0], o0);
        o1 = fmaf(ha[h4 * 4 + 1], s_w5[h4 * 4 + 1], o1);
        o2 = fmaf(ha[h4 * 4 + 2], s_w5[h4 * 4 + 2], o2);
        o3 = fmaf(ha[h4 * 4 + 3], s_w5[h4 * 4 + 3], o3);
    }
    out[row * D_NETS + d] = (o0 + o1) + (o2 + o3) + s_b5;
}

// ---------------------------------------------------------------------------
// NEW PATH kernels (layer-wise, acts in ws as packed split-bf16).
// Act pack layout == W pack layout: addr = ((g*64 + ks)*64 + lane)*8 + kk,
// lane = khalf*32 + (row&31), element (row = g*32+(lane&31),
// k = ks*16 + (lane>>5)*8 + kk).
// ---------------------------------------------------------------------------

// layer1: Y1 = relu(x[:, :16] @ gW1^T + gb1), written packed. fp32 VALU.
__global__ __launch_bounds__(256) void g_layer1(
    const float* __restrict__ x,
    const float* __restrict__ gW1, const float* __restrict__ gb1,
    ushort* __restrict__ Yh, ushort* __restrict__ Yl, int row_base)
{
    __shared__ float s_x[32 * 17];   // padded: conflict-free scalar reads
    __shared__ float s_w[64][16];
    __shared__ float s_b[64];

    const int t   = threadIdx.x;
    const int bid = blockIdx.x;
    const int g   = bid >> 4;             // chunk-local 32-row group
    const int ks0 = (bid & 15) * 4;       // 4 ks per block -> 64 cols

    for (int i = t; i < 512; i += 256) {
        const int r = i >> 4, c = i & 15;
        s_x[r * 17 + c] = x[(size_t)(row_base + g * 32 + r) * 32 + c];
    }
    {
        const int n_i = t >> 2, c = t & 3;
        *(float4*)&s_w[n_i][c * 4] =
            *(const float4*)&gW1[(ks0 * 16 + n_i) * 16 + c * 4];
    }
    if (t < 64) s_b[t] = gb1[ks0 * 16 + t];
    __syncthreads();

    const int lane = t & 63;
    const int ks   = ks0 + (t >> 6);
    const int r31  = lane & 31;
    const int nl0  = (t >> 6) * 16 + (lane >> 5) * 8;

    float xr[16];
    #pragma unroll
    for (int k = 0; k < 16; ++k) xr[k] = s_x[r31 * 17 + k];

    bf16x8 hv, lv;
    #pragma unroll
    for (int kk = 0; kk < 8; ++kk) {
        const float* wr_ = s_w[nl0 + kk];
        float a = s_b[nl0 + kk];
        #pragma unroll
        for (int k = 0; k < 16; ++k) a = fmaf(xr[k], wr_[k], a);
        a = fmaxf(a, 0.f);
        ushort h = bf16_rne(a);
        hv[kk] = (short)h;
        lv[kk] = (short)bf16_rne(a - bf16_to_f(h));
    }
    const int dst = ((g * 64 + ks) * 64 + lane) * 8;
    *(bf16x8*)&Yh[dst] = hv;
    *(bf16x8*)&Yl[dst] = lv;
}

// big layer: Y = relu(A @ W^T + b), A and Y packed split-bf16, W packed.
// grid = (CH/128 row-tiles) * 8 col-panels; bid&7 = panel (XCD-aligned:
// 512 KB W panel stays in that XCD's L2). 8 waves (4r x 2c), wave = 32x64.
__global__ __launch_bounds__(512, 4) void g_big(
    const ushort* __restrict__ Ah, const ushort* __restrict__ Al,
    const ushort* __restrict__ Wh, const ushort* __restrict__ Wl,
    const float* __restrict__ bias,
    ushort* __restrict__ Yh, ushort* __restrict__ Yl)
{
    __shared__ ushort scr[8][2][32 * 40];   // per-wave hi/lo transpose scratch

    const int t     = threadIdx.x;
    const int l     = t & 63;
    const int wv    = t >> 6;       // 0..7
    const int wr    = wv >> 1;      // 0..3
    const int wc    = wv & 1;       // 0..1
    const int bid   = blockIdx.x;
    const int panel = bid & 7;      // col panel (128 cols), one per XCD
    const int rt    = bid >> 3;     // row tile (128 rows)

    const int gA  = rt * 4 + wr;            // A row-group (32 rows)
    const int gB0 = panel * 4 + wc * 2;     // B col-groups gB0, gB0+1

    const int aBase = gA * 32768 + l * 8;   // + ks*512
    const int bBase = gB0 * 512 + l * 8;    // + ks*16384 (+512 for tc=1)

    f32x16 acc0[2], acc1[2];
    #pragma unroll
    for (int tc = 0; tc < 2; ++tc) {
        const float bv = bias[panel * 128 + wc * 64 + tc * 32 + (l & 31)];
        #pragma unroll
        for (int r = 0; r < 16; ++r) { acc0[tc][r] = bv; acc1[tc][r] = 0.f; }
    }

    bf16x8 a_h0, a_l0, bh00, bh01, bl00, bl01;
    bf16x8 a_h1, a_l1, bh10, bh11, bl10, bl11;

#define LD(ks, AH, AL, BH0, BH1, BL0, BL1)                         \
    {                                                              \
        const int _a = aBase + (ks) * 512;                         \
        const int _b = bBase + (ks) * 16384;                       \
        AH  = *(const bf16x8*)&Ah[_a];                             \
        AL  = *(const bf16x8*)&Al[_a];                             \
        BH0 = *(const bf16x8*)&Wh[_b];                             \
        BH1 = *(const bf16x8*)&Wh[_b + 512];                       \
        BL0 = *(const bf16x8*)&Wl[_b];                             \
        BL1 = *(const bf16x8*)&Wl[_b + 512];                       \
    }

#define MM(AH, AL, BH0, BH1, BL0, BL1)                             \
    {                                                              \
        acc0[0] = MFMA(AH, BH0, acc0[0], 0, 0, 0);                 \
        acc0[1] = MFMA(AH, BH1, acc0[1], 0, 0, 0);                 \
        acc1[0] = MFMA(AL, BH0, acc1[0], 0, 0, 0);                 \
        acc1[1] = MFMA(AL, BH1, acc1[1], 0, 0, 0);                 \
        acc1[0] = MFMA(AH, BL0, acc1[0], 0, 0, 0);                 \
        acc1[1] = MFMA(AH, BL1, acc1[1], 0, 0, 0);                 \
    }

    LD(0, a_h0, a_l0, bh00, bh01, bl00, bl01);
    #pragma unroll 2
    for (int ks = 0; ks < 64; ks += 2) {
        if (ks + 1 < 64) LD(ks + 1, a_h1, a_l1, bh10, bh11, bl10, bl11);
        MM(a_h0, a_l0, bh00, bh01, bl00, bl01);
        if (ks + 2 < 64) LD(ks + 2, a_h0, a_l0, bh00, bh01, bl00, bl01);
        MM(a_h1, a_l1, bh10, bh11, bl10, bl11);
    }
#undef LD
#undef MM

    // epilogue: relu + split + transpose to act-pack layout
    const int lc = l & 31, lh = l >> 5;
    ushort* scrh = &scr[wv][0][0];
    ushort* scrl = &scr[wv][1][0];
    #pragma unroll 1
    for (int tc = 0; tc < 2; ++tc) {
        __syncthreads();
        #pragma unroll
        for (int r = 0; r < 16; ++r) {
            const int row = (r & 3) + 8 * (r >> 2) + 4 * lh;
            float v = fmaxf(acc0[tc][r] + acc1[tc][r], 0.0f);
            ushort h = bf16_rne(v);
            scrh[row * 40 + lc] = h;
            scrl[row * 40 + lc] = bf16_rne(v - bf16_to_f(h));
        }
        __syncthreads();
        const int ks0 = panel * 8 + wc * 4 + tc * 2;
        #pragma unroll
        for (int ss = 0; ss < 2; ++ss) {
            const int c = ss * 16 + lh * 8;
            bf16x8 hv = *(const bf16x8*)&scrh[lc * 40 + c];
            bf16x8 lv = *(const bf16x8*)&scrl[lc * 40 + c];
            const int dst = ((gA * 64 + ks0 + ss) * 64 + l) * 8;
            *(bf16x8*)&Yh[dst] = hv;
            *(bf16x8*)&Yl[dst] = lv;
        }
    }
}

// layer5: out_g = act4 . gW5 + gb5, act4 packed.
__global__ __launch_bounds__(256) void g_layer5(
    const ushort* __restrict__ Ah, const ushort* __restrict__ Al,
    const float* __restrict__ gW5, const float* __restrict__ gb5,
    float* __restrict__ out, int row_base)
{
    __shared__ float s_w5[1024];
    const int t = threadIdx.x;
    #pragma unroll
    for (int i = 0; i < 4; ++i) s_w5[t + i * 256] = gW5[t + i * 256];
    __syncthreads();

    const int l  = t & 63;
    const int wv = t >> 6;
    const int g  = blockIdx.x * 4 + wv;
    const int lh = l >> 5;

    float s = 0.f;
    #pragma unroll 4
    for (int ks = 0; ks < 64; ++ks) {
        const int idx = ((g * 64 + ks) * 64 + l) * 8;
        bf16x8 hv = *(const bf16x8*)&Ah[idx];
        bf16x8 lv = *(const bf16x8*)&Al[idx];
        const float* w = &s_w5[ks * 16 + lh * 8];
        #pragma unroll
        for (int kk = 0; kk < 8; ++kk) {
            float a = bf16_to_f((ushort)hv[kk]) + bf16_to_f((ushort)lv[kk]);
            s = fmaf(a, w[kk], s);
        }
    }
    s += __shfl_xor(s, 32);
    if (lh == 0)
        out[B_ROWS * D_NETS + row_base + g * 32 + l] = s + gb5[0];
}

// ---------------------------------------------------------------------------
// FALLBACK: fused g-kernel from round 4 (used when ws_size is too small).
// ---------------------------------------------------------------------------
__global__ __launch_bounds__(1024, 4) void g_net_mfma(
    const float* __restrict__ x,
    const ushort* __restrict__ ws,
    const float* __restrict__ gb1, const float* __restrict__ gb2,
    const float* __restrict__ gb3, const float* __restrict__ gb4,
    const float* __restrict__ gW5, const float* __restrict__ gb5,
    float* __restrict__ out)
{
    __shared__ ushort s_Ah[32 * 1024];
    __shared__ ushort s_Al[32 * 1024];
    __shared__ ushort s_xh[32 * 16];
    __shared__ ushort s_xl[32 * 16];
    __shared__ float  s_red[1024];

    const int t    = threadIdx.x;
    const int l    = t & 63;
    const int wv   = t >> 6;
    const int row0 = blockIdx.x * 32;
    const int n0   = wv * 64;
    const int lr   = l & 31;
    const int lk   = l >> 5;
    const int lk8  = lk * 8;
    const int akey = lr << 3;

    const int wbase0 = ((wv * 2 + 0) * 64 + l) * 8;
    const int wbase1 = ((wv * 2 + 1) * 64 + l) * 8;

    if (t < 512) {
        const int r = t >> 4, c = t & 15;
        float v = x[(row0 + r) * 32 + c];
        ushort h = bf16_rne(v);
        s_xh[r * 16 + c] = h;
        s_xl[r * 16 + c] = bf16_rne(v - bf16_to_f(h));
    }
    __syncthreads();

    f32x16 acc[2];

    {
        const ushort* W1h = ws + 6 * MW;
        const ushort* W1l = W1h + 16384;
        bf16x8 ah = *(const bf16x8*)&s_xh[lr * 16 + lk8];
        bf16x8 al = *(const bf16x8*)&s_xl[lr * 16 + lk8];
        #pragma unroll
        for (int nt = 0; nt < 2; ++nt) {
            const int n = n0 + nt * 32 + lr;
            bf16x8 bh = *(const bf16x8*)&W1h[n * 16 + lk8];
            bf16x8 bl = *(const bf16x8*)&W1l[n * 16 + lk8];
            const float bv = gb1[n];
            f32x16 a;
            #pragma unroll
            for (int r = 0; r < 16; ++r) a[r] = bv;
            a = MFMA(ah, bh, a, 0, 0, 0);
            a = MFMA(al, bh, a, 0, 0, 0);
            a = MFMA(ah, bl, a, 0, 0, 0);
            acc[nt] = a;
        }
        #pragma unroll
        for (int nt = 0; nt < 2; ++nt) {
            const int nc = n0 + nt * 32 + lr;
            #pragma unroll
            for (int r = 0; r < 16; ++r) {
                const int row = (r & 3) + 8 * (r >> 2) + 4 * lk;
                float v2 = fmaxf(acc[nt][r], 0.0f);
                ushort h = bf16_rne(v2);
                const int idx = row * 1024 + (nc ^ ((row & 31) << 3));
                s_Ah[idx] = h;
                s_Al[idx] = bf16_rne(v2 - bf16_to_f(h));
            }
        }
    }
    __syncthreads();

    const int abase = lr * 1024;

#define LOADB(ks, BH, BL)                                               \
    {                                                                   \
        const int _o = (ks) * 16384;                                    \
        BH[0] = *(const bf16x8*)&Wh[_o + wbase0];                       \
        BL[0] = *(const bf16x8*)&Wl[_o + wbase0];                       \
        BH[1] = *(const bf16x8*)&Wh[_o + wbase1];                       \
        BL[1] = *(const bf16x8*)&Wl[_o + wbase1];                       \
    }
#define LOADA(ks, AH, AL)                                               \
    {                                                                   \
        const int _ai = abase + (((ks) * 16 + lk8) ^ akey);             \
        AH = *(const bf16x8*)&s_Ah[_ai];                                \
        AL = *(const bf16x8*)&s_Al[_ai];                                \
    }
#define DOMFMA(AH, AL, BH, BL)                                          \
    {                                                                   \
        _Pragma("unroll")                                               \
        for (int nt = 0; nt < 2; ++nt) {                                \
            acc[nt] = MFMA(AH, BH[nt], acc[nt], 0, 0, 0);               \
            acc[nt] = MFMA(AL, BH[nt], acc[nt], 0, 0, 0);               \
            acc[nt] = MFMA(AH, BL[nt], acc[nt], 0, 0, 0);               \
        }                                                               \
    }

    #pragma unroll 1
    for (int L = 0; L < 3; ++L) {
        const ushort* Wh = ws + (size_t)(2 * L) * MW;
        const ushort* Wl = ws + (size_t)(2 * L + 1) * MW;
        const float* gbL = (L == 0) ? gb2 : ((L == 1) ? gb3 : gb4);

        #pragma unroll
        for (int nt = 0; nt < 2; ++nt) {
            const float bv = gbL[n0 + nt * 32 + lr];
            #pragma unroll
            for (int r = 0; r < 16; ++r) acc[nt][r] = bv;
        }

        bf16x8 Bh0[2], Bl0[2], Bh1[2], Bl1[2], Bh2[2], Bl2[2], Bh3[2], Bl3[2];
        bf16x8 Ah0, Al0, Ah1, Al1, Ah2, Al2, Ah3, Al3;

        LOADB(0, Bh0, Bl0);
        LOADB(1, Bh1, Bl1);
        LOADB(2, Bh2, Bl2);
        LOADA(0, Ah0, Al0);
        LOADA(1, Ah1, Al1);

        #pragma unroll 1
        for (int ks = 0; ks < 64; ks += 4) {
            int s2 = ks + 2; s2 = s2 > 63 ? 63 : s2;
            int s3 = ks + 3; s3 = s3 > 63 ? 63 : s3;
            int s4 = ks + 4; s4 = s4 > 63 ? 63 : s4;
            int s5 = ks + 5; s5 = s5 > 63 ? 63 : s5;
            int s6 = ks + 6; s6 = s6 > 63 ? 63 : s6;

            LOADB(s3, Bh3, Bl3);  LOADA(s2, Ah2, Al2);
            DOMFMA(Ah0, Al0, Bh0, Bl0);
            LOADB(s4, Bh0, Bl0);  LOADA(s3, Ah3, Al3);
            DOMFMA(Ah1, Al1, Bh1, Bl1);
            LOADB(s5, Bh1, Bl1);  LOADA(s4, Ah0, Al0);
            DOMFMA(Ah2, Al2, Bh2, Bl2);
            LOADB(s6, Bh2, Bl2);  LOADA(s5, Ah1, Al1);
            DOMFMA(Ah3, Al3, Bh3, Bl3);
        }

        __syncthreads();
        #pragma unroll
        for (int nt = 0; nt < 2; ++nt) {
            const int nc = n0 + nt * 32 + lr;
            #pragma unroll
            for (int r = 0; r < 16; ++r) {
                const int row = (r & 3) + 8 * (r >> 2) + 4 * lk;
                float v2 = fmaxf(acc[nt][r], 0.0f);
                ushort h = bf16_rne(v2);
                const int idx = row * 1024 + (nc ^ ((row & 31) << 3));
                s_Ah[idx] = h;
                s_Al[idx] = bf16_rne(v2 - bf16_to_f(h));
            }
        }
        __syncthreads();
    }
#undef LOADB
#undef LOADA
#undef DOMFMA

    {
        const int r = t >> 5;
        const int c = t & 31;
        const int rkey = (r & 31) << 3;
        float s = 0.0f;
        #pragma unroll 8
        for (int q = 0; q < 32; ++q) {
            const int k = c * 32 + q;
            const int idx = r * 1024 + (k ^ rkey);
            float a = bf16_to_f(s_Ah[idx]) + bf16_to_f(s_Al[idx]);
            s = fmaf(a, gW5[k], s);
        }
        s_red[t] = s;
    }
    __syncthreads();
    if (t < 32) {
        float sum = gb5[0];
        #pragma unroll
        for (int c = 0; c < 32; ++c) sum += s_red[t * 32 + c];
        out[B_ROWS * D_NETS + row0 + t] = sum;
    }
}

extern "C" void kernel_launch(void* const* d_in, const int* in_sizes, int n_in,
                              void* d_out, int out_size, void* d_ws, size_t ws_size,
                              hipStream_t stream) {
    (void)in_sizes; (void)n_in; (void)out_size;

    const float* x   = (const float*)d_in[0];
    const float* hW1 = (const float*)d_in[1];
    const float* hb1 = (const float*)d_in[2];
    const float* hW2 = (const float*)d_in[3];
    const float* hb2 = (const float*)d_in[4];
    const float* hW3 = (const float*)d_in[5];
    const float* hb3 = (const float*)d_in[6];
    const float* hW4 = (const float*)d_in[7];
    const float* hb4 = (const float*)d_in[8];
    const float* hW5 = (const float*)d_in[9];
    const float* hb5 = (const float*)d_in[10];
    const float* gW1 = (const float*)d_in[11];
    const float* gb1 = (const float*)d_in[12];
    const float* gW2 = (const float*)d_in[13];
    const float* gb2 = (const float*)d_in[14];
    const float* gW3 = (const float*)d_in[15];
    const float* gb3 = (const float*)d_in[16];
    const float* gW4 = (const float*)d_in[17];
    const float* gb4 = (const float*)d_in[18];
    const float* gW5 = (const float*)d_in[19];
    const float* gb5 = (const float*)d_in[20];
    float* out = (float*)d_out;
    ushort* wsp = (ushort*)d_ws;

    pack_weights<<<(3 * PKL + 2048 + 255) / 256, 256, 0, stream>>>(gW1, gW2, gW3, gW4, wsp);

    dim3 gh(B_ROWS / 256, D_NETS);
    h_net_kernel<<<gh, 256, 0, stream>>>(x, hW1, hb1, hW2, hb2, hW3, hb3,
                                         hW4, hb4, hW5, hb5, out);

    // choose act chunk size to fit ws; fall back to fused kernel if tiny ws
    size_t CH = 0;
    for (size_t c = 32768; c >= 4096; c >>= 1) {
        size_t need = 2ull * (8ull * MW + 4ull * c * 1024ull);
        if (ws_size >= need) { CH = c; break; }
    }

    if (CH == 0) {
        g_net_mfma<<<B_ROWS / 32, 1024, 0, stream>>>(x, wsp, gb1, gb2, gb3, gb4,
                                                     gW5, gb5, out);
        return;
    }

    const size_t CHM = CH * 1024;
    ushort* A0h = wsp + 8 * (size_t)MW;
    ushort* A0l = A0h + CHM;
    ushort* A1h = A0l + CHM;
    ushort* A1l = A1h + CHM;

    const ushort* W2h = wsp;            const ushort* W2l = wsp + 1 * (size_t)MW;
    const ushort* W3h = wsp + 2 * (size_t)MW; const ushort* W3l = wsp + 3 * (size_t)MW;
    const ushort* W4h = wsp + 4 * (size_t)MW; const ushort* W4l = wsp + 5 * (size_t)MW;

    for (int row_base = 0; row_base < B_ROWS; row_base += (int)CH) {
        const int nblk1 = (int)(CH / 2);          // (CH/32 groups) * 16
        g_layer1<<<nblk1, 256, 0, stream>>>(x, gW1, gb1, A0h, A0l, row_base);

        const int nbig = (int)(CH / 128) * 8;
        g_big<<<nbig, 512, 0, stream>>>(A0h, A0l, W2h, W2l, gb2, A1h, A1l);
        g_big<<<nbig, 512, 0, stream>>>(A1h, A1l, W3h, W3l, gb3, A0h, A0l);
        g_big<<<nbig, 512, 0, stream>>>(A0h, A0l, W4h, W4l, gb4, A1h, A1l);

        g_layer5<<<(int)(CH / 128), 256, 0, stream>>>(A1h, A1l, gW5, gb5, out, row_base);
    }
}

// Round 6
// 339.699 us; speedup vs baseline: 3.7155x; 3.7155x over previous
//
#include <hip/hip_runtime.h>

#define B_ROWS 32768
#define D_NETS 16
#define MWH    1048576              // halfs per packed 1024x1024 layer
#define GW1OFF (3 * MWH)            // gW1 pack offset (halfs)
#define HPOFF  (GW1OFF + 16384)     // h-net pack offset (halfs)

typedef _Float16 half8 __attribute__((ext_vector_type(8)));
typedef __attribute__((ext_vector_type(16))) float f32x16;

#define MFMA16 __builtin_amdgcn_mfma_f32_32x32x16_f16

// ---------------------------------------------------------------------------
// pack: all weights -> fp16, MFMA-fragment-linear packed.
// Big layers: Wpack[((ks*32+g)*64 + l)*8 + kk], element n = g*32+(l&31),
// k = ks*16 + (l>>5)*8 + kk.  gW1: [ks=0 only] 32 g-groups.  h-nets: per
// (d,L): 8 chunks [(ks*2+g)*64+l]*8.
// ---------------------------------------------------------------------------
__global__ void pack_f16(const float* __restrict__ gW1,
                         const float* __restrict__ gW2,
                         const float* __restrict__ gW3,
                         const float* __restrict__ gW4,
                         const float* __restrict__ hW2,
                         const float* __restrict__ hW3,
                         const float* __restrict__ hW4,
                         _Float16* __restrict__ ws) {
    const int p = blockIdx.x * 256 + threadIdx.x;
    const float* src;
    size_t dst;
    if (p < 393216) {                       // gW2/3/4: 3 x 131072 chunks
        const int lz = p >> 17;
        const int pl = p & 131071;
        const float* W = (lz == 0) ? gW2 : (lz == 1) ? gW3 : gW4;
        const int l = pl & 63, g = (pl >> 6) & 31, ks = pl >> 11;
        src = &W[(size_t)(g * 32 + (l & 31)) * 1024 + ks * 16 + (l >> 5) * 8];
        dst = (size_t)lz * MWH + (size_t)pl * 8;
    } else if (p < 395264) {                // gW1: 2048 chunks
        const int q = p - 393216;
        const int l = q & 63, g = q >> 6;
        src = &gW1[(g * 32 + (l & 31)) * 16 + (l >> 5) * 8];
        dst = GW1OFF + (size_t)q * 8;
    } else {                                // hW2/3/4: 24576 chunks
        const int q = p - 395264;
        const int l = q & 63;
        const int sub = (q >> 6) & 7;       // ks*2+g
        const int ks = sub >> 1, g = sub & 1;
        const int dL = q >> 9;              // d*3+L
        const int d = dL / 3, L = dL - d * 3;
        const float* W = (L == 0) ? hW2 : (L == 1) ? hW3 : hW4;
        src = &W[d * 4096 + (g * 32 + (l & 31)) * 64 + ks * 16 + (l >> 5) * 8];
        dst = HPOFF + (size_t)q * 8;
    }
    half8 v;
    #pragma unroll
    for (int kk = 0; kk < 8; ++kk) v[kk] = (_Float16)src[kk];
    *(half8*)&ws[dst] = v;
}

// ---------------------------------------------------------------------------
// h-network on MFMA. grid (B/128, 16); block 256 = 4 waves; wave = 32 rows.
// Acts in LDS fragment-pack [rg4][ks4][l64][8] (wave-local, ks-XOR swizzle).
// Layer 1 (outer product) and layer 5 (64-dot) on VALU fp32.
// ---------------------------------------------------------------------------
__global__ __launch_bounds__(256, 4) void h_net_mfma(
    const float* __restrict__ x,
    const float* __restrict__ hW1, const float* __restrict__ hb1,
    const float* __restrict__ hb2, const float* __restrict__ hb3,
    const float* __restrict__ hb4,
    const float* __restrict__ hW5, const float* __restrict__ hb5,
    const _Float16* __restrict__ ws,
    float* __restrict__ out)
{
    __shared__ _Float16 sA[8192];            // 16 KiB act pack
    __shared__ float s_w1[64], s_b1[64], s_bs[3][64], s_w5[64];

    const int t = threadIdx.x;
    const int d = blockIdx.y;
    const int row0 = blockIdx.x * 128;
    const int l = t & 63, wv = t >> 6;
    const int l31 = l & 31, lk = l >> 5;

    if (t < 64) {
        s_w1[t]    = hW1[d * 64 + t];
        s_b1[t]    = hb1[d * 64 + t];
        s_bs[0][t] = hb2[d * 64 + t];
        s_bs[1][t] = hb3[d * 64 + t];
        s_bs[2][t] = hb4[d * 64 + t];
        s_w5[t]    = hW5[d * 64 + t];
    }
    __syncthreads();

    // ---- layer 1: h1 = relu(sv * w1 + b1), scatter to act pack ----
    {
        const int row = t >> 1, jh = t & 1, rg = row >> 5, r31 = row & 31;
        const float sv = x[(size_t)(row0 + row) * 32 + 16 + d];
        #pragma unroll
        for (int jj = 0; jj < 32; ++jj) {
            const int j = jh * 32 + jj;
            const float a = fmaxf(fmaf(sv, s_w1[j], s_b1[j]), 0.f);
            const int ks = j >> 4;
            const int li = ((((j >> 3) & 1) << 5) | r31) ^ (ks << 3);
            sA[((rg * 4 + ks) * 64 + li) * 8 + (j & 7)] = (_Float16)a;
        }
    }
    __syncthreads();

    const _Float16* hp = ws + HPOFF + (size_t)d * 3 * 4096;

    // ---- layers 2..4: 64x64 MFMA ----
    #pragma unroll 1
    for (int L = 0; L < 3; ++L) {
        const _Float16* W = hp + (size_t)L * 4096;
        half8 B[4][2], A[4];
        #pragma unroll
        for (int ks = 0; ks < 4; ++ks) {
            B[ks][0] = *(const half8*)&W[((ks * 2 + 0) * 64 + l) * 8];
            B[ks][1] = *(const half8*)&W[((ks * 2 + 1) * 64 + l) * 8];
            A[ks] = *(const half8*)&sA[((wv * 4 + ks) * 64 + (l ^ (ks << 3))) * 8];
        }
        f32x16 acc[2];
        #pragma unroll
        for (int nt = 0; nt < 2; ++nt) {
            const float bv = s_bs[L][nt * 32 + l31];
            #pragma unroll
            for (int r = 0; r < 16; ++r) acc[nt][r] = bv;
        }
        #pragma unroll
        for (int ks = 0; ks < 4; ++ks) {
            acc[0] = MFMA16(A[ks], B[ks][0], acc[0], 0, 0, 0);
            acc[1] = MFMA16(A[ks], B[ks][1], acc[1], 0, 0, 0);
        }
        __syncthreads();
        #pragma unroll
        for (int nt = 0; nt < 2; ++nt) {
            #pragma unroll
            for (int r = 0; r < 16; ++r) {
                const int r31 = (r & 3) + 8 * (r >> 2) + 4 * lk;
                const int col = nt * 32 + l31;
                const float v = fmaxf(acc[nt][r], 0.f);
                const int ks = col >> 4;
                const int li = ((((col >> 3) & 1) << 5) | r31) ^ (ks << 3);
                sA[((wv * 4 + ks) * 64 + li) * 8 + (col & 7)] = (_Float16)v;
            }
        }
        __syncthreads();
    }

    // ---- layer 5: out_h[row, d] ----
    {
        const int row = t >> 1, jh = t & 1, rg = row >> 5, r31 = row & 31;
        float s = 0.f;
        #pragma unroll
        for (int ks2 = 0; ks2 < 2; ++ks2) {
            const int ks = jh * 2 + ks2;
            #pragma unroll
            for (int h2 = 0; h2 < 2; ++h2) {
                const int li = ((h2 << 5) | r31) ^ (ks << 3);
                half8 v = *(const half8*)&sA[((rg * 4 + ks) * 64 + li) * 8];
                const float* w = &s_w5[ks * 16 + h2 * 8];
                #pragma unroll
                for (int kk = 0; kk < 8; ++kk)
                    s = fmaf((float)v[kk], w[kk], s);
            }
        }
        s += __shfl_xor(s, 1);
        if (jh == 0) out[(size_t)(row0 + row) * 16 + d] = s + hb5[d];
    }
}

// ---------------------------------------------------------------------------
// g-network fused, single fp16. grid B/64 = 512; block 1024 = 16 waves.
// Wave wv owns cols [wv*64, wv*64+64) for all 64 rows. Acts (64x1024 fp16)
// in LDS fragment-pack [rg2][ks64][l64][8] with ks-XOR lane swizzle.
// W streams from packed ws (coalesced 1KB/load), 2-deep pipelined.
// ---------------------------------------------------------------------------
__global__ __launch_bounds__(1024, 4) void g_fused_f16(
    const float* __restrict__ x,
    const _Float16* __restrict__ ws,
    const float* __restrict__ gb1, const float* __restrict__ gb2,
    const float* __restrict__ gb3, const float* __restrict__ gb4,
    const float* __restrict__ gW5, const float* __restrict__ gb5,
    float* __restrict__ out)
{
    __shared__ _Float16 sA[65536];           // 128 KiB
    __shared__ float s_w5f[1024];
    __shared__ float s_red[1024];

    const int t = threadIdx.x;
    const int l = t & 63, wv = t >> 6;
    const int l31 = l & 31, lk = l >> 5;
    const int n0 = wv * 64;
    const int row0 = blockIdx.x * 64;

    s_w5f[t] = gW5[t];

    f32x16 acc[2][2];

#define G_EPI()                                                              \
    {                                                                        \
        _Pragma("unroll")                                                    \
        for (int rg = 0; rg < 2; ++rg)                                       \
            _Pragma("unroll")                                                \
            for (int nt = 0; nt < 2; ++nt) {                                 \
                const int col = n0 + nt * 32 + l31;                          \
                const int ks = col >> 4;                                     \
                const int kh = ((col >> 3) & 1) << 5;                        \
                const int key = (ks & 3) << 3;                               \
                _Pragma("unroll")                                            \
                for (int r = 0; r < 16; ++r) {                               \
                    const int r31 = (r & 3) + 8 * (r >> 2) + 4 * lk;         \
                    const float v = fmaxf(acc[rg][nt][r], 0.f);              \
                    sA[((rg * 64 + ks) * 64 + ((kh | r31) ^ key)) * 8 +      \
                       (col & 7)] = (_Float16)v;                             \
                }                                                            \
            }                                                                \
    }

    // ---- layer 1 (K=16) ----
    {
        half8 ax[2];
        #pragma unroll
        for (int rg = 0; rg < 2; ++rg) {
            const float* xp = &x[(size_t)(row0 + rg * 32 + l31) * 32 + lk * 8];
            #pragma unroll
            for (int kk = 0; kk < 8; ++kk) ax[rg][kk] = (_Float16)xp[kk];
        }
        #pragma unroll
        for (int nt = 0; nt < 2; ++nt) {
            half8 b = *(const half8*)&ws[GW1OFF + ((wv * 2 + nt) * 64 + l) * 8];
            const float bv = gb1[n0 + nt * 32 + l31];
            #pragma unroll
            for (int rg = 0; rg < 2; ++rg) {
                #pragma unroll
                for (int r = 0; r < 16; ++r) acc[rg][nt][r] = bv;
                acc[rg][nt] = MFMA16(ax[rg], b, acc[rg][nt], 0, 0, 0);
            }
        }
    }
    G_EPI();
    __syncthreads();

    // ---- layers 2..4 ----
#define G_LA(ks, A_)                                                         \
    { const int _k = (ks); const int _key = (_k & 3) << 3;                   \
      A_[0] = *(const half8*)&sA[(_k * 64 + (l ^ _key)) * 8];                \
      A_[1] = *(const half8*)&sA[((64 + _k) * 64 + (l ^ _key)) * 8]; }

#define G_LB(ks, B_)                                                         \
    { const int _o = (ks) * 16384;                                           \
      B_[0] = *(const half8*)&W[_o + ((wv * 2 + 0) * 64 + l) * 8];           \
      B_[1] = *(const half8*)&W[_o + ((wv * 2 + 1) * 64 + l) * 8]; }

#define G_MM(A_, B_)                                                         \
    { acc[0][0] = MFMA16(A_[0], B_[0], acc[0][0], 0, 0, 0);                  \
      acc[0][1] = MFMA16(A_[0], B_[1], acc[0][1], 0, 0, 0);                  \
      acc[1][0] = MFMA16(A_[1], B_[0], acc[1][0], 0, 0, 0);                  \
      acc[1][1] = MFMA16(A_[1], B_[1], acc[1][1], 0, 0, 0); }

    #pragma unroll 1
    for (int L = 0; L < 3; ++L) {
        const _Float16* W = ws + (size_t)L * MWH;
        const float* gbL = (L == 0) ? gb2 : (L == 1) ? gb3 : gb4;

        #pragma unroll
        for (int nt = 0; nt < 2; ++nt) {
            const float bv = gbL[n0 + nt * 32 + l31];
            #pragma unroll
            for (int rg = 0; rg < 2; ++rg)
                #pragma unroll
                for (int r = 0; r < 16; ++r) acc[rg][nt][r] = bv;
        }

        half8 A0[2], B0[2], A1[2], B1[2];
        G_LA(0, A0); G_LB(0, B0);
        G_LA(1, A1); G_LB(1, B1);

        #pragma unroll 1
        for (int ks = 0; ks < 64; ks += 2) {
            G_MM(A0, B0);
            if (ks + 2 < 64) { G_LA(ks + 2, A0); G_LB(ks + 2, B0); }
            G_MM(A1, B1);
            if (ks + 3 < 64) { G_LA(ks + 3, A1); G_LB(ks + 3, B1); }
        }

        __syncthreads();     // all waves done reading sA
        G_EPI();
        __syncthreads();     // sA ready for next consumer
    }
#undef G_LA
#undef G_LB
#undef G_MM
#undef G_EPI

    // ---- layer 5: out_g ----
    {
        const int row = t >> 4, c = t & 15;
        const int rg = row >> 5, r31 = row & 31;
        float s = 0.f;
        #pragma unroll
        for (int kq = 0; kq < 4; ++kq) {
            const int ks = c * 4 + kq;
            const int key = (ks & 3) << 3;
            #pragma unroll
            for (int h2 = 0; h2 < 2; ++h2) {
                const int li = ((h2 << 5) | r31) ^ key;
                half8 v = *(const half8*)&sA[((rg * 64 + ks) * 64 + li) * 8];
                const float* w = &s_w5f[ks * 16 + h2 * 8];
                #pragma unroll
                for (int kk = 0; kk < 8; ++kk)
                    s = fmaf((float)v[kk], w[kk], s);
            }
        }
        s_red[t] = s;
    }
    __syncthreads();
    if (t < 64) {
        float s = gb5[0];
        #pragma unroll
        for (int c = 0; c < 16; ++c) s += s_red[t * 16 + c];
        out[(size_t)B_ROWS * D_NETS + row0 + t] = s;
    }
}

extern "C" void kernel_launch(void* const* d_in, const int* in_sizes, int n_in,
                              void* d_out, int out_size, void* d_ws, size_t ws_size,
                              hipStream_t stream) {
    (void)in_sizes; (void)n_in; (void)out_size; (void)ws_size;

    const float* x   = (const float*)d_in[0];
    const float* hW1 = (const float*)d_in[1];
    const float* hb1 = (const float*)d_in[2];
    const float* hW2 = (const float*)d_in[3];
    const float* hb2 = (const float*)d_in[4];
    const float* hW3 = (const float*)d_in[5];
    const float* hb3 = (const float*)d_in[6];
    const float* hW4 = (const float*)d_in[7];
    const float* hb4 = (const float*)d_in[8];
    const float* hW5 = (const float*)d_in[9];
    const float* hb5 = (const float*)d_in[10];
    const float* gW1 = (const float*)d_in[11];
    const float* gb1 = (const float*)d_in[12];
    const float* gW2 = (const float*)d_in[13];
    const float* gb2 = (const float*)d_in[14];
    const float* gW3 = (const float*)d_in[15];
    const float* gb3 = (const float*)d_in[16];
    const float* gW4 = (const float*)d_in[17];
    const float* gb4 = (const float*)d_in[18];
    const float* gW5 = (const float*)d_in[19];
    const float* gb5 = (const float*)d_in[20];
    float* out = (float*)d_out;
    _Float16* wsh = (_Float16*)d_ws;

    pack_f16<<<1640, 256, 0, stream>>>(gW1, gW2, gW3, gW4, hW2, hW3, hW4, wsh);

    dim3 gh(B_ROWS / 128, D_NETS);
    h_net_mfma<<<gh, 256, 0, stream>>>(x, hW1, hb1, hb2, hb3, hb4,
                                       hW5, hb5, wsh, out);

    g_fused_f16<<<B_ROWS / 64, 1024, 0, stream>>>(x, wsh, gb1, gb2, gb3, gb4,
                                                  gW5, gb5, out);
}

// Round 7
// 314.978 us; speedup vs baseline: 4.0071x; 1.0785x over previous
//
#include <hip/hip_runtime.h>

#define B_ROWS 32768
#define D_NETS 16
#define MWH    1048576              // halfs per packed 1024x1024 layer
#define GW1OFF (3 * MWH)            // gW1 pack offset (halfs)
#define HPOFF  (GW1OFF + 16384)     // h-net pack offset (halfs)

typedef _Float16 half8 __attribute__((ext_vector_type(8)));
typedef _Float16 half4 __attribute__((ext_vector_type(4)));
typedef __attribute__((ext_vector_type(16))) float f32x16;

#define MFMA16 __builtin_amdgcn_mfma_f32_32x32x16_f16

// ---------------------------------------------------------------------------
// pack: all weights -> fp16, MFMA-fragment-linear packed (A-operand layout:
// lane = khalf*32 + (n&31), 8 consecutive k per lane).
// ---------------------------------------------------------------------------
__global__ void pack_f16(const float* __restrict__ gW1,
                         const float* __restrict__ gW2,
                         const float* __restrict__ gW3,
                         const float* __restrict__ gW4,
                         const float* __restrict__ hW2,
                         const float* __restrict__ hW3,
                         const float* __restrict__ hW4,
                         _Float16* __restrict__ ws) {
    const int p = blockIdx.x * 256 + threadIdx.x;
    const float* src;
    size_t dst;
    if (p < 393216) {                       // gW2/3/4: 3 x 131072 chunks
        const int lz = p >> 17;
        const int pl = p & 131071;
        const float* W = (lz == 0) ? gW2 : (lz == 1) ? gW3 : gW4;
        const int l = pl & 63, g = (pl >> 6) & 31, ks = pl >> 11;
        src = &W[(size_t)(g * 32 + (l & 31)) * 1024 + ks * 16 + (l >> 5) * 8];
        dst = (size_t)lz * MWH + (size_t)pl * 8;
    } else if (p < 395264) {                // gW1: 2048 chunks
        const int q = p - 393216;
        const int l = q & 63, g = q >> 6;
        src = &gW1[(g * 32 + (l & 31)) * 16 + (l >> 5) * 8];
        dst = GW1OFF + (size_t)q * 8;
    } else {                                // hW2/3/4: 24576 chunks
        const int q = p - 395264;
        const int l = q & 63;
        const int sub = (q >> 6) & 7;       // ks*2+g
        const int ks = sub >> 1, g = sub & 1;
        const int dL = q >> 9;              // d*3+L
        const int d = dL / 3, L = dL - d * 3;
        const float* W = (L == 0) ? hW2 : (L == 1) ? hW3 : hW4;
        src = &W[d * 4096 + (g * 32 + (l & 31)) * 64 + ks * 16 + (l >> 5) * 8];
        dst = HPOFF + (size_t)q * 8;
    }
    half8 v;
    #pragma unroll
    for (int kk = 0; kk < 8; ++kk) v[kk] = (_Float16)src[kk];
    *(half8*)&ws[dst] = v;
}

// ---------------------------------------------------------------------------
// h-network on MFMA (unchanged from round 6; small share of runtime).
// ---------------------------------------------------------------------------
__global__ __launch_bounds__(256, 4) void h_net_mfma(
    const float* __restrict__ x,
    const float* __restrict__ hW1, const float* __restrict__ hb1,
    const float* __restrict__ hb2, const float* __restrict__ hb3,
    const float* __restrict__ hb4,
    const float* __restrict__ hW5, const float* __restrict__ hb5,
    const _Float16* __restrict__ ws,
    float* __restrict__ out)
{
    __shared__ _Float16 sA[8192];
    __shared__ float s_w1[64], s_b1[64], s_bs[3][64], s_w5[64];

    const int t = threadIdx.x;
    const int d = blockIdx.y;
    const int row0 = blockIdx.x * 128;
    const int l = t & 63, wv = t >> 6;
    const int l31 = l & 31, lk = l >> 5;

    if (t < 64) {
        s_w1[t]    = hW1[d * 64 + t];
        s_b1[t]    = hb1[d * 64 + t];
        s_bs[0][t] = hb2[d * 64 + t];
        s_bs[1][t] = hb3[d * 64 + t];
        s_bs[2][t] = hb4[d * 64 + t];
        s_w5[t]    = hW5[d * 64 + t];
    }
    __syncthreads();

    {
        const int row = t >> 1, jh = t & 1, rg = row >> 5, r31 = row & 31;
        const float sv = x[(size_t)(row0 + row) * 32 + 16 + d];
        #pragma unroll
        for (int jj = 0; jj < 32; ++jj) {
            const int j = jh * 32 + jj;
            const float a = fmaxf(fmaf(sv, s_w1[j], s_b1[j]), 0.f);
            const int ks = j >> 4;
            const int li = ((((j >> 3) & 1) << 5) | r31) ^ (ks << 3);
            sA[((rg * 4 + ks) * 64 + li) * 8 + (j & 7)] = (_Float16)a;
        }
    }
    __syncthreads();

    const _Float16* hp = ws + HPOFF + (size_t)d * 3 * 4096;

    #pragma unroll 1
    for (int L = 0; L < 3; ++L) {
        const _Float16* W = hp + (size_t)L * 4096;
        half8 B[4][2], A[4];
        #pragma unroll
        for (int ks = 0; ks < 4; ++ks) {
            B[ks][0] = *(const half8*)&W[((ks * 2 + 0) * 64 + l) * 8];
            B[ks][1] = *(const half8*)&W[((ks * 2 + 1) * 64 + l) * 8];
            A[ks] = *(const half8*)&sA[((wv * 4 + ks) * 64 + (l ^ (ks << 3))) * 8];
        }
        f32x16 acc[2];
        #pragma unroll
        for (int nt = 0; nt < 2; ++nt) {
            const float bv = s_bs[L][nt * 32 + l31];
            #pragma unroll
            for (int r = 0; r < 16; ++r) acc[nt][r] = bv;
        }
        #pragma unroll
        for (int ks = 0; ks < 4; ++ks) {
            acc[0] = MFMA16(A[ks], B[ks][0], acc[0], 0, 0, 0);
            acc[1] = MFMA16(A[ks], B[ks][1], acc[1], 0, 0, 0);
        }
        __syncthreads();
        #pragma unroll
        for (int nt = 0; nt < 2; ++nt) {
            #pragma unroll
            for (int r = 0; r < 16; ++r) {
                const int r31 = (r & 3) + 8 * (r >> 2) + 4 * lk;
                const int col = nt * 32 + l31;
                const float v = fmaxf(acc[nt][r], 0.f);
                const int ks = col >> 4;
                const int li = ((((col >> 3) & 1) << 5) | r31) ^ (ks << 3);
                sA[((wv * 4 + ks) * 64 + li) * 8 + (col & 7)] = (_Float16)v;
            }
        }
        __syncthreads();
    }

    {
        const int row = t >> 1, jh = t & 1, rg = row >> 5, r31 = row & 31;
        float s = 0.f;
        #pragma unroll
        for (int ks2 = 0; ks2 < 2; ++ks2) {
            const int ks = jh * 2 + ks2;
            #pragma unroll
            for (int h2 = 0; h2 < 2; ++h2) {
                const int li = ((h2 << 5) | r31) ^ (ks << 3);
                half8 v = *(const half8*)&sA[((rg * 4 + ks) * 64 + li) * 8];
                const float* w = &s_w5[ks * 16 + h2 * 8];
                #pragma unroll
                for (int kk = 0; kk < 8; ++kk)
                    s = fmaf((float)v[kk], w[kk], s);
            }
        }
        s += __shfl_xor(s, 1);
        if (jh == 0) out[(size_t)(row0 + row) * 16 + d] = s + hb5[d];
    }
}

// ---------------------------------------------------------------------------
// g-network fused v2: SWAPPED operands. C[n][act_row] = W (A) x act^T (B).
// grid B/64 = 512; block 1024 = 16 waves. Wave (rg = wv>>3, cg = wv&7) owns
// n in [cg*128, cg*128+128) x act rows [rg*32, rg*32+32).
// Acts in LDS pack sA[rg][ks][lane=kh*32|row31][8k] -- B-frag b128 reads are
// contiguous 1KB (conflict-free, no swizzle). Epilogue: reg-dim = n = next k,
// so 4 consecutive k assemble into one b64 store (16 stores/thread/layer).
// W streams from packed global (coalesced 1KB/frag), 2-deep pipelined.
// ---------------------------------------------------------------------------
__global__ __launch_bounds__(1024, 4) void g_fused_v2(
    const float* __restrict__ x,
    const _Float16* __restrict__ ws,
    const float* __restrict__ gb1, const float* __restrict__ gb2,
    const float* __restrict__ gb3, const float* __restrict__ gb4,
    const float* __restrict__ gW5, const float* __restrict__ gb5,
    float* __restrict__ out)
{
    __shared__ _Float16 sA[65536];     // 128 KiB act pack
    __shared__ float s_w5f[1024];
    __shared__ float s_red[1024];

    const int t = threadIdx.x;
    const int l = t & 63, wv = t >> 6;
    const int l31 = l & 31, lk = l >> 5;
    const int rg = wv >> 3;          // act-row group (32 rows)
    const int cg = wv & 7;           // n group (128 n)
    const int n0 = cg * 128;
    const int row0 = blockIdx.x * 64;

    s_w5f[t] = gW5[t];

    f32x16 acc[4];

    // acc[nt][r] holds C[n][row]: n = n0+nt*32+(r&3)+8*(r>>2)+4*lk, row=l31.
#define G_EPI()                                                              \
    {                                                                        \
        _Pragma("unroll")                                                    \
        for (int nt = 0; nt < 4; ++nt) {                                     \
            _Pragma("unroll")                                                \
            for (int q = 0; q < 4; ++q) {                                    \
                half4 v;                                                     \
                _Pragma("unroll")                                            \
                for (int j = 0; j < 4; ++j)                                  \
                    v[j] = (_Float16)fmaxf(acc[nt][q * 4 + j], 0.f);         \
                const int ksn = cg * 8 + nt * 2 + (q >> 1);                  \
                const int li  = ((q & 1) << 5) | l31;                        \
                *(half4*)&sA[((rg * 64 + ksn) * 64 + li) * 8 + lk * 4] = v;  \
            }                                                                \
        }                                                                    \
    }

    // ---- layer 1 (K=16, one MFMA per nt) ----
    {
        half8 xb;
        {
            const float* xp = &x[(size_t)(row0 + rg * 32 + l31) * 32 + lk * 8];
            #pragma unroll
            for (int kk = 0; kk < 8; ++kk) xb[kk] = (_Float16)xp[kk];
        }
        #pragma unroll
        for (int nt = 0; nt < 4; ++nt) {
            #pragma unroll
            for (int r = 0; r < 16; ++r)
                acc[nt][r] = gb1[n0 + nt * 32 + (r & 3) + 8 * (r >> 2) + 4 * lk];
            half8 wb = *(const half8*)&ws[GW1OFF + ((cg * 4 + nt) * 64 + l) * 8];
            acc[nt] = MFMA16(wb, xb, acc[nt], 0, 0, 0);
        }
    }
    G_EPI();
    __syncthreads();

    // ---- layers 2..4 ----
#define G_LA(ks, A_)  A_ = *(const half8*)&sA[((rg * 64 + (ks)) * 64 + l) * 8];
#define G_LB(ks, B_)                                                         \
    { const int _o = (ks) * 16384 + cg * 2048 + l * 8;                       \
      B_[0] = *(const half8*)&W[_o];                                         \
      B_[1] = *(const half8*)&W[_o + 512];                                   \
      B_[2] = *(const half8*)&W[_o + 1024];                                  \
      B_[3] = *(const half8*)&W[_o + 1536]; }
#define G_MM(A_, B_)                                                         \
    { acc[0] = MFMA16(B_[0], A_, acc[0], 0, 0, 0);                           \
      acc[1] = MFMA16(B_[1], A_, acc[1], 0, 0, 0);                           \
      acc[2] = MFMA16(B_[2], A_, acc[2], 0, 0, 0);                           \
      acc[3] = MFMA16(B_[3], A_, acc[3], 0, 0, 0); }

    #pragma unroll 1
    for (int L = 0; L < 3; ++L) {
        const _Float16* W = ws + (size_t)L * MWH;
        const float* gbL = (L == 0) ? gb2 : (L == 1) ? gb3 : gb4;

        half8 A0, A1, B0[4], B1[4];
        G_LA(0, A0); G_LB(0, B0);
        G_LA(1, A1); G_LB(1, B1);

        #pragma unroll
        for (int nt = 0; nt < 4; ++nt)
            #pragma unroll
            for (int r = 0; r < 16; ++r)
                acc[nt][r] = gbL[n0 + nt * 32 + (r & 3) + 8 * (r >> 2) + 4 * lk];

        #pragma unroll 1
        for (int ks = 0; ks < 64; ks += 2) {
            G_MM(A0, B0);
            if (ks + 2 < 64) { G_LA(ks + 2, A0); G_LB(ks + 2, B0); }
            G_MM(A1, B1);
            if (ks + 3 < 64) { G_LA(ks + 3, A1); G_LB(ks + 3, B1); }
        }

        __syncthreads();     // all waves done reading sA
        G_EPI();
        __syncthreads();     // sA ready for next layer
    }
#undef G_LA
#undef G_LB
#undef G_MM
#undef G_EPI

    // ---- layer 5: out_g[row] = act . gW5 + gb5 ----
    {
        const int row = t & 63;
        const int rg5 = row >> 5, r31 = row & 31;
        const int c = t >> 6;          // 0..15: 64-n chunk
        float s = 0.f;
        #pragma unroll
        for (int q = 0; q < 4; ++q) {
            #pragma unroll
            for (int kh = 0; kh < 2; ++kh) {
                half8 v = *(const half8*)&sA[((rg5 * 64 + c * 4 + q) * 64 +
                                             ((kh << 5) | r31)) * 8];
                const float* w = &s_w5f[(c * 4 + q) * 16 + kh * 8];
                #pragma unroll
                for (int kk = 0; kk < 8; ++kk)
                    s = fmaf((float)v[kk], w[kk], s);
            }
        }
        s_red[t] = s;
    }
    __syncthreads();
    if (t < 64) {
        float s = gb5[0];
        #pragma unroll
        for (int c = 0; c < 16; ++c) s += s_red[c * 64 + t];
        out[(size_t)B_ROWS * D_NETS + row0 + t] = s;
    }
}

extern "C" void kernel_launch(void* const* d_in, const int* in_sizes, int n_in,
                              void* d_out, int out_size, void* d_ws, size_t ws_size,
                              hipStream_t stream) {
    (void)in_sizes; (void)n_in; (void)out_size; (void)ws_size;

    const float* x   = (const float*)d_in[0];
    const float* hW1 = (const float*)d_in[1];
    const float* hb1 = (const float*)d_in[2];
    const float* hW2 = (const float*)d_in[3];
    const float* hb2 = (const float*)d_in[4];
    const float* hW3 = (const float*)d_in[5];
    const float* hb3 = (const float*)d_in[6];
    const float* hW4 = (const float*)d_in[7];
    const float* hb4 = (const float*)d_in[8];
    const float* hW5 = (const float*)d_in[9];
    const float* hb5 = (const float*)d_in[10];
    const float* gW1 = (const float*)d_in[11];
    const float* gb1 = (const float*)d_in[12];
    const float* gW2 = (const float*)d_in[13];
    const float* gb2 = (const float*)d_in[14];
    const float* gW3 = (const float*)d_in[15];
    const float* gb3 = (const float*)d_in[16];
    const float* gW4 = (const float*)d_in[17];
    const float* gb4 = (const float*)d_in[18];
    const float* gW5 = (const float*)d_in[19];
    const float* gb5 = (const float*)d_in[20];
    float* out = (float*)d_out;
    _Float16* wsh = (_Float16*)d_ws;

    pack_f16<<<1640, 256, 0, stream>>>(gW1, gW2, gW3, gW4, hW2, hW3, hW4, wsh);

    dim3 gh(B_ROWS / 128, D_NETS);
    h_net_mfma<<<gh, 256, 0, stream>>>(x, hW1, hb1, hb2, hb3, hb4,
                                       hW5, hb5, wsh, out);

    g_fused_v2<<<B_ROWS / 64, 1024, 0, stream>>>(x, wsh, gb1, gb2, gb3, gb4,
                                                 gW5, gb5, out);
}

// Round 8
// 264.018 us; speedup vs baseline: 4.7806x; 1.1930x over previous
//
#include <hip/hip_runtime.h>

#define B_ROWS 32768
#define D_NETS 16
#define MWH    1048576              // halfs per packed 1024x1024 layer
#define GW1OFF (3 * MWH)            // gW1 pack offset (halfs)
#define HPOFF  (GW1OFF + 16384)     // h-net pack offset (halfs)

typedef _Float16 half8 __attribute__((ext_vector_type(8)));
typedef _Float16 half4 __attribute__((ext_vector_type(4)));
typedef __attribute__((ext_vector_type(16))) float f32x16;

#define MFMA16 __builtin_amdgcn_mfma_f32_32x32x16_f16

// ---------------------------------------------------------------------------
// pack: all weights -> fp16, MFMA-fragment-linear packed (A-operand layout:
// lane = khalf*32 + (n&31), 8 consecutive k per lane).
// ---------------------------------------------------------------------------
__global__ void pack_f16(const float* __restrict__ gW1,
                         const float* __restrict__ gW2,
                         const float* __restrict__ gW3,
                         const float* __restrict__ gW4,
                         const float* __restrict__ hW2,
                         const float* __restrict__ hW3,
                         const float* __restrict__ hW4,
                         _Float16* __restrict__ ws) {
    const int p = blockIdx.x * 256 + threadIdx.x;
    const float* src;
    size_t dst;
    if (p < 393216) {                       // gW2/3/4: 3 x 131072 chunks
        const int lz = p >> 17;
        const int pl = p & 131071;
        const float* W = (lz == 0) ? gW2 : (lz == 1) ? gW3 : gW4;
        const int l = pl & 63, g = (pl >> 6) & 31, ks = pl >> 11;
        src = &W[(size_t)(g * 32 + (l & 31)) * 1024 + ks * 16 + (l >> 5) * 8];
        dst = (size_t)lz * MWH + (size_t)pl * 8;
    } else if (p < 395264) {                // gW1: 2048 chunks
        const int q = p - 393216;
        const int l = q & 63, g = q >> 6;
        src = &gW1[(g * 32 + (l & 31)) * 16 + (l >> 5) * 8];
        dst = GW1OFF + (size_t)q * 8;
    } else {                                // hW2/3/4: 24576 chunks
        const int q = p - 395264;
        const int l = q & 63;
        const int sub = (q >> 6) & 7;       // ks*2+g
        const int ks = sub >> 1, g = sub & 1;
        const int dL = q >> 9;              // d*3+L
        const int d = dL / 3, L = dL - d * 3;
        const float* W = (L == 0) ? hW2 : (L == 1) ? hW3 : hW4;
        src = &W[d * 4096 + (g * 32 + (l & 31)) * 64 + ks * 16 + (l >> 5) * 8];
        dst = HPOFF + (size_t)q * 8;
    }
    half8 v;
    #pragma unroll
    for (int kk = 0; kk < 8; ++kk) v[kk] = (_Float16)src[kk];
    *(half8*)&ws[dst] = v;
}

// ---------------------------------------------------------------------------
// h-network on MFMA (unchanged; small share of runtime).
// ---------------------------------------------------------------------------
__global__ __launch_bounds__(256, 4) void h_net_mfma(
    const float* __restrict__ x,
    const float* __restrict__ hW1, const float* __restrict__ hb1,
    const float* __restrict__ hb2, const float* __restrict__ hb3,
    const float* __restrict__ hb4,
    const float* __restrict__ hW5, const float* __restrict__ hb5,
    const _Float16* __restrict__ ws,
    float* __restrict__ out)
{
    __shared__ _Float16 sA[8192];
    __shared__ float s_w1[64], s_b1[64], s_bs[3][64], s_w5[64];

    const int t = threadIdx.x;
    const int d = blockIdx.y;
    const int row0 = blockIdx.x * 128;
    const int l = t & 63, wv = t >> 6;
    const int l31 = l & 31, lk = l >> 5;

    if (t < 64) {
        s_w1[t]    = hW1[d * 64 + t];
        s_b1[t]    = hb1[d * 64 + t];
        s_bs[0][t] = hb2[d * 64 + t];
        s_bs[1][t] = hb3[d * 64 + t];
        s_bs[2][t] = hb4[d * 64 + t];
        s_w5[t]    = hW5[d * 64 + t];
    }
    __syncthreads();

    {
        const int row = t >> 1, jh = t & 1, rg = row >> 5, r31 = row & 31;
        const float sv = x[(size_t)(row0 + row) * 32 + 16 + d];
        #pragma unroll
        for (int jj = 0; jj < 32; ++jj) {
            const int j = jh * 32 + jj;
            const float a = fmaxf(fmaf(sv, s_w1[j], s_b1[j]), 0.f);
            const int ks = j >> 4;
            const int li = ((((j >> 3) & 1) << 5) | r31) ^ (ks << 3);
            sA[((rg * 4 + ks) * 64 + li) * 8 + (j & 7)] = (_Float16)a;
        }
    }
    __syncthreads();

    const _Float16* hp = ws + HPOFF + (size_t)d * 3 * 4096;

    #pragma unroll 1
    for (int L = 0; L < 3; ++L) {
        const _Float16* W = hp + (size_t)L * 4096;
        half8 B[4][2], A[4];
        #pragma unroll
        for (int ks = 0; ks < 4; ++ks) {
            B[ks][0] = *(const half8*)&W[((ks * 2 + 0) * 64 + l) * 8];
            B[ks][1] = *(const half8*)&W[((ks * 2 + 1) * 64 + l) * 8];
            A[ks] = *(const half8*)&sA[((wv * 4 + ks) * 64 + (l ^ (ks << 3))) * 8];
        }
        f32x16 acc[2];
        #pragma unroll
        for (int nt = 0; nt < 2; ++nt) {
            const float bv = s_bs[L][nt * 32 + l31];
            #pragma unroll
            for (int r = 0; r < 16; ++r) acc[nt][r] = bv;
        }
        #pragma unroll
        for (int ks = 0; ks < 4; ++ks) {
            acc[0] = MFMA16(A[ks], B[ks][0], acc[0], 0, 0, 0);
            acc[1] = MFMA16(A[ks], B[ks][1], acc[1], 0, 0, 0);
        }
        __syncthreads();
        #pragma unroll
        for (int nt = 0; nt < 2; ++nt) {
            #pragma unroll
            for (int r = 0; r < 16; ++r) {
                const int r31 = (r & 3) + 8 * (r >> 2) + 4 * lk;
                const int col = nt * 32 + l31;
                const float v = fmaxf(acc[nt][r], 0.f);
                const int ks = col >> 4;
                const int li = ((((col >> 3) & 1) << 5) | r31) ^ (ks << 3);
                sA[((wv * 4 + ks) * 64 + li) * 8 + (col & 7)] = (_Float16)v;
            }
        }
        __syncthreads();
    }

    {
        const int row = t >> 1, jh = t & 1, rg = row >> 5, r31 = row & 31;
        float s = 0.f;
        #pragma unroll
        for (int ks2 = 0; ks2 < 2; ++ks2) {
            const int ks = jh * 2 + ks2;
            #pragma unroll
            for (int h2 = 0; h2 < 2; ++h2) {
                const int li = ((h2 << 5) | r31) ^ (ks << 3);
                half8 v = *(const half8*)&sA[((rg * 4 + ks) * 64 + li) * 8];
                const float* w = &s_w5[ks * 16 + h2 * 8];
                #pragma unroll
                for (int kk = 0; kk < 8; ++kk)
                    s = fmaf((float)v[kk], w[kk], s);
            }
        }
        s += __shfl_xor(s, 1);
        if (jh == 0) out[(size_t)(row0 + row) * 16 + d] = s + hb5[d];
    }
}

// ---------------------------------------------------------------------------
// g-network fused v3: swapped operands, 1rg x 16cg wave tiling.
// grid B/64 = 512; block 1024 = 16 waves. Wave wv owns n in [wv*64, wv*64+64)
// for ALL 64 act rows -> W read ONCE per block (3.2 GB total W stream).
// acc[nt][rg] (4 x f32x16, AGPR). Acts in LDS pack
// sA[rg][ksn][lane=kh*32|row31][8k] -- conflict-free b128 reads, no swizzle.
// Epilogue: reg-dim = n = next k -> half4 (b64) stores.
// ---------------------------------------------------------------------------
__global__ __launch_bounds__(1024, 4) void g_fused_v3(
    const float* __restrict__ x,
    const _Float16* __restrict__ ws,
    const float* __restrict__ gb1, const float* __restrict__ gb2,
    const float* __restrict__ gb3, const float* __restrict__ gb4,
    const float* __restrict__ gW5, const float* __restrict__ gb5,
    float* __restrict__ out)
{
    __shared__ _Float16 sA[65536];     // 128 KiB act pack
    __shared__ float s_w5f[1024];
    __shared__ float s_red[1024];

    const int t = threadIdx.x;
    const int l = t & 63, wv = t >> 6;
    const int l31 = l & 31, lk = l >> 5;
    const int n0 = wv * 64;
    const int row0 = blockIdx.x * 64;

    s_w5f[t] = gW5[t];

    f32x16 acc[2][2];   // [nt][rg]

    // acc[nt][rg][r] = C[n][row]: n = n0+nt*32+(r&3)+8*(r>>2)+4*lk,
    // row = rg*32 + l31.
#define G_EPI()                                                              \
    {                                                                        \
        _Pragma("unroll")                                                    \
        for (int nt = 0; nt < 2; ++nt) {                                     \
            _Pragma("unroll")                                                \
            for (int rg = 0; rg < 2; ++rg) {                                 \
                _Pragma("unroll")                                            \
                for (int q = 0; q < 4; ++q) {                                \
                    half4 v;                                                 \
                    _Pragma("unroll")                                        \
                    for (int j = 0; j < 4; ++j)                              \
                        v[j] = (_Float16)fmaxf(acc[nt][rg][q * 4 + j], 0.f); \
                    const int ksn = wv * 4 + nt * 2 + (q >> 1);              \
                    const int li  = ((q & 1) << 5) | l31;                    \
                    *(half4*)&sA[((rg * 64 + ksn) * 64 + li) * 8 + lk * 4] = v; \
                }                                                            \
            }                                                                \
        }                                                                    \
    }

    // ---- layer 1 (K=16) ----
    {
        half8 xb[2];
        #pragma unroll
        for (int rg = 0; rg < 2; ++rg) {
            const float* xp = &x[(size_t)(row0 + rg * 32 + l31) * 32 + lk * 8];
            #pragma unroll
            for (int kk = 0; kk < 8; ++kk) xb[rg][kk] = (_Float16)xp[kk];
        }
        #pragma unroll
        for (int nt = 0; nt < 2; ++nt) {
            half8 wb = *(const half8*)&ws[GW1OFF + ((wv * 2 + nt) * 64 + l) * 8];
            #pragma unroll
            for (int rg = 0; rg < 2; ++rg) {
                #pragma unroll
                for (int r = 0; r < 16; ++r)
                    acc[nt][rg][r] =
                        gb1[n0 + nt * 32 + (r & 3) + 8 * (r >> 2) + 4 * lk];
                acc[nt][rg] = MFMA16(wb, xb[rg], acc[nt][rg], 0, 0, 0);
            }
        }
    }
    G_EPI();
    __syncthreads();

    // ---- layers 2..4 ----
#define G_LA(ks, A_)                                                         \
    { A_[0] = *(const half8*)&sA[((ks) * 64 + l) * 8];                       \
      A_[1] = *(const half8*)&sA[((64 + (ks)) * 64 + l) * 8]; }
#define G_LB(ks, B_)                                                         \
    { const int _o = (ks) * 16384 + wv * 1024 + l * 8;                       \
      B_[0] = *(const half8*)&W[_o];                                         \
      B_[1] = *(const half8*)&W[_o + 512]; }
#define G_MM(A_, B_)                                                         \
    { acc[0][0] = MFMA16(B_[0], A_[0], acc[0][0], 0, 0, 0);                  \
      acc[0][1] = MFMA16(B_[0], A_[1], acc[0][1], 0, 0, 0);                  \
      acc[1][0] = MFMA16(B_[1], A_[0], acc[1][0], 0, 0, 0);                  \
      acc[1][1] = MFMA16(B_[1], A_[1], acc[1][1], 0, 0, 0); }

    #pragma unroll 1
    for (int L = 0; L < 3; ++L) {
        const _Float16* W = ws + (size_t)L * MWH;
        const float* gbL = (L == 0) ? gb2 : (L == 1) ? gb3 : gb4;

        half8 A0[2], A1[2], B0[2], B1[2];
        G_LA(0, A0); G_LB(0, B0);
        G_LA(1, A1); G_LB(1, B1);

        #pragma unroll
        for (int nt = 0; nt < 2; ++nt)
            #pragma unroll
            for (int rg = 0; rg < 2; ++rg)
                #pragma unroll
                for (int r = 0; r < 16; ++r)
                    acc[nt][rg][r] =
                        gbL[n0 + nt * 32 + (r & 3) + 8 * (r >> 2) + 4 * lk];

        #pragma unroll 1
        for (int ks = 0; ks < 64; ks += 2) {
            G_MM(A0, B0);
            if (ks + 2 < 64) { G_LA(ks + 2, A0); G_LB(ks + 2, B0); }
            G_MM(A1, B1);
            if (ks + 3 < 64) { G_LA(ks + 3, A1); G_LB(ks + 3, B1); }
        }

        __syncthreads();     // all waves done reading sA
        G_EPI();
        __syncthreads();     // sA ready for next layer
    }
#undef G_LA
#undef G_LB
#undef G_MM
#undef G_EPI

    // ---- layer 5: out_g[row] = act . gW5 + gb5 ----
    {
        const int row = t & 63;
        const int rg5 = row >> 5, r31 = row & 31;
        const int c = t >> 6;          // 0..15: 64-n chunk
        float s = 0.f;
        #pragma unroll
        for (int q = 0; q < 4; ++q) {
            #pragma unroll
            for (int kh = 0; kh < 2; ++kh) {
                half8 v = *(const half8*)&sA[((rg5 * 64 + c * 4 + q) * 64 +
                                             ((kh << 5) | r31)) * 8];
                const float* w = &s_w5f[(c * 4 + q) * 16 + kh * 8];
                #pragma unroll
                for (int kk = 0; kk < 8; ++kk)
                    s = fmaf((float)v[kk], w[kk], s);
            }
        }
        s_red[t] = s;
    }
    __syncthreads();
    if (t < 64) {
        float s = gb5[0];
        #pragma unroll
        for (int c = 0; c < 16; ++c) s += s_red[c * 64 + t];
        out[(size_t)B_ROWS * D_NETS + row0 + t] = s;
    }
}

extern "C" void kernel_launch(void* const* d_in, const int* in_sizes, int n_in,
                              void* d_out, int out_size, void* d_ws, size_t ws_size,
                              hipStream_t stream) {
    (void)in_sizes; (void)n_in; (void)out_size; (void)ws_size;

    const float* x   = (const float*)d_in[0];
    const float* hW1 = (const float*)d_in[1];
    const float* hb1 = (const float*)d_in[2];
    const float* hW2 = (const float*)d_in[3];
    const float* hb2 = (const float*)d_in[4];
    const float* hW3 = (const float*)d_in[5];
    const float* hb3 = (const float*)d_in[6];
    const float* hW4 = (const float*)d_in[7];
    const float* hb4 = (const float*)d_in[8];
    const float* hW5 = (const float*)d_in[9];
    const float* hb5 = (const float*)d_in[10];
    const float* gW1 = (const float*)d_in[11];
    const float* gb1 = (const float*)d_in[12];
    const float* gW2 = (const float*)d_in[13];
    const float* gb2 = (const float*)d_in[14];
    const float* gW3 = (const float*)d_in[15];
    const float* gb3 = (const float*)d_in[16];
    const float* gW4 = (const float*)d_in[17];
    const float* gb4 = (const float*)d_in[18];
    const float* gW5 = (const float*)d_in[19];
    const float* gb5 = (const float*)d_in[20];
    float* out = (float*)d_out;
    _Float16* wsh = (_Float16*)d_ws;

    pack_f16<<<1640, 256, 0, stream>>>(gW1, gW2, gW3, gW4, hW2, hW3, hW4, wsh);

    dim3 gh(B_ROWS / 128, D_NETS);
    h_net_mfma<<<gh, 256, 0, stream>>>(x, hW1, hb1, hb2, hb3, hb4,
                                       hW5, hb5, wsh, out);

    g_fused_v3<<<B_ROWS / 64, 1024, 0, stream>>>(x, wsh, gb1, gb2, gb3, gb4,
                                                 gW5, gb5, out);
}